// Round 5
// baseline (301.211 us; speedup 1.0000x reference)
//
#include <hip/hip_runtime.h>

// WordAttention: B=8, S=2048, D_IN=D_H=512, fp32 in/out.
// R12 (resubmit; prior bench died to container-acquire infra failure, no
// kernel signal). Fused attention phase-engine upgrade over R11 (125us,
// MfmaUtil 23%):
//  - Ring-4 staging (4x32KB), loads issued 2 phases ahead, vmcnt(8) counted
//    waits -> L2 latency (~200-500cy) fully off the critical path.
//    slot(p)=u&3 is compile-time (8*kt = 0 mod 4).
//  - ONE barrier per phase (was 2): with reuse distance 4, the slot written
//    at p+2-top was last read at p-2, ordered by barrier p-1 already.
//    lgkmcnt(0) kept only after the Ps write (u==3).
//  - Full Q hoist: qf[2][16] (128 VGPR) - QKT phases read only K (8 b128);
//    frees 32KB Qh -> pays for ring slot 3. LDS 145KB, 1 block/CU, VGPR<=256
//    free at 2 waves/SIMD.
//  - Numerics identical to R11 (verified): unnormalized p=exp(s) bf16,
//    no online max; rowsum shuffle+LDS reduce; normalize in epilogue.
// Phase map per k-tile: u0..3 = QKT on K d-units (S^T += K_u x Q_u),
// u3 tail: exp->Ps[64q][128k]; u4..7 = PV on V k-units (tiled layout).
// Stage targets (p+2): u0->K2, u1->K3, u2->V0, u3->V1, u4->V2, u5->V3,
// u6->K0', u7->K1' (kt<15).

typedef __attribute__((ext_vector_type(8))) _Float16 f16x8;
typedef __attribute__((ext_vector_type(8))) short bf16x8;
typedef __attribute__((ext_vector_type(4))) float f32x4;

__device__ __forceinline__ unsigned short f2h(float f) {
  _Float16 h = (_Float16)f;
  return *(unsigned short*)&h;
}
__device__ __forceinline__ unsigned short f2bf(float f) {
  unsigned int u = __float_as_uint(f);
  unsigned int r = (u + 0x7fffu + ((u >> 16) & 1u)) >> 16;
  return (unsigned short)r;
}
__device__ __forceinline__ float bf2f(unsigned short h) {
  return __uint_as_float(((unsigned int)h) << 16);
}

__device__ __forceinline__ void load_lds16(const void* g, void* l) {
  __builtin_amdgcn_global_load_lds(
      (const __attribute__((address_space(1))) unsigned int*)g,
      (__attribute__((address_space(3))) unsigned int*)l, 16, 0, 0);
}

// ---- x fp32 -> fp16 ----
__global__ __launch_bounds__(256) void convx_kernel(const float* __restrict__ x,
                                                    unsigned short* __restrict__ xh) {
  int i = blockIdx.x * 256 + threadIdx.x;
  float4 v = ((const float4*)x)[i];
  union { unsigned short h[4]; short4 s4; } u;
  u.h[0] = f2h(v.x); u.h[1] = f2h(v.y); u.h[2] = f2h(v.z); u.h[3] = f2h(v.w);
  ((short4*)xh)[i] = u.s4;
}

// ---- W [d][h] fp32 -> Wt [h][d] fp16; z = 0,1,2 selects Wq/Wk/Wv ----
__global__ __launch_bounds__(256) void convw_kernel(
    const float* __restrict__ W0, const float* __restrict__ W1,
    const float* __restrict__ W2, unsigned short* __restrict__ Wt) {
  const float* W = (blockIdx.z == 0) ? W0 : (blockIdx.z == 1) ? W1 : W2;
  unsigned short* t = Wt + (size_t)blockIdx.z * 512 * 512;
  __shared__ float tile[32][33];
  int tx = threadIdx.x, ty = threadIdx.y;  // 32 x 8
  int h0 = blockIdx.x * 32, d0 = blockIdx.y * 32;
  for (int i = ty; i < 32; i += 8) tile[i][tx] = W[(long)(d0 + i) * 512 + h0 + tx];
  __syncthreads();
  for (int i = ty; i < 32; i += 8)
    t[(long)(h0 + i) * 512 + d0 + tx] = f2h(tile[tx][i]);
}

// ---- fused QKV projection: [16384,512] x [512,1536]^T + bias.
//      cols 0..511 -> Qo fp16; 512..1023 -> Ko fp16;
//      1024..1535 -> V tiled bf16: Vt[b][s/32][d][s%32].
__global__ __launch_bounds__(256) void gemm_qkv_kernel(
    const unsigned short* __restrict__ A,   // xh [16384][512] fp16
    const unsigned short* __restrict__ Bt,  // Wt [1536][512] fp16
    unsigned short* __restrict__ Qo, unsigned short* __restrict__ Ko,
    unsigned short* __restrict__ VTo,
    const float* __restrict__ bq, const float* __restrict__ bk,
    const float* __restrict__ bv) {
  __shared__ alignas(16) unsigned short As[128 * 32];
  __shared__ alignas(16) unsigned short Bs[128 * 32];
  const int t = threadIdx.x;
  const long long bm = (long long)blockIdx.x * 128;
  const long long bn = (long long)blockIdx.y * 128;

  const int ar = t >> 2;
  const int ac = (t & 3) * 8;

  f32x4 acc[4][4];
#pragma unroll
  for (int i = 0; i < 4; i++)
#pragma unroll
    for (int j = 0; j < 4; j++) acc[i][j] = {0.f, 0.f, 0.f, 0.f};

  const int lane = t & 63;
  const int wave = t >> 6;
  const int wm = (wave & 1) * 64;
  const int wn = (wave >> 1) * 64;
  const int fm = lane & 15;
  const int k8 = (lane >> 4) * 8;

  for (int kt = 0; kt < 512; kt += 32) {
#pragma unroll
    for (int r = 0; r < 2; r++)
      load_lds16(A + (bm + r * 64 + ar) * 512 + kt + ac, &As[r * 2048 + t * 8]);
#pragma unroll
    for (int r = 0; r < 2; r++)
      load_lds16(Bt + (bn + r * 64 + ar) * 512 + kt + ac, &Bs[r * 2048 + t * 8]);
    __syncthreads();

    f16x8 af[4], bfr[4];
#pragma unroll
    for (int i = 0; i < 4; i++)
      af[i] = *(const f16x8*)&As[(wm + i * 16 + fm) * 32 + k8];
#pragma unroll
    for (int j = 0; j < 4; j++)
      bfr[j] = *(const f16x8*)&Bs[(wn + j * 16 + fm) * 32 + k8];
#pragma unroll
    for (int i = 0; i < 4; i++)
#pragma unroll
      for (int j = 0; j < 4; j++)
        acc[i][j] = __builtin_amdgcn_mfma_f32_16x16x32_f16(af[i], bfr[j], acc[i][j], 0, 0, 0);
    __syncthreads();
  }

  const int crow = (lane >> 4) * 4;  // C/D: col=lane&15, row=(lane>>4)*4+reg
  const int ccol = lane & 15;
#pragma unroll
  for (int j = 0; j < 4; j++) {
    const long long col = bn + wn + j * 16 + ccol;
    float bias = (col < 512) ? bq[col] : (col < 1024) ? bk[col - 512] : bv[col - 1024];
#pragma unroll
    for (int i = 0; i < 4; i++) {
      const long long row0 = bm + wm + i * 16 + crow;
      if (col >= 1024) {
        const long long b = row0 >> 11;
        const long long s = row0 & 2047;
        const long long dcol = col - 1024;
        union { unsigned short h[4]; short4 s4; } u;
#pragma unroll
        for (int r = 0; r < 4; r++) u.h[r] = f2bf(acc[i][j][r] + bias);  // V -> bf16
        // tiled: Vt[b][s/32][d][s%32]; short4 spans 4 consecutive s in-block
        *(short4*)(VTo + (((b * 64 + (s >> 5)) * 512 + dcol) * 32 + (s & 31))) = u.s4;
      } else {
        unsigned short* dst = (col < 512) ? (Qo + row0 * 512 + col)
                                          : (Ko + row0 * 512 + (col - 512));
#pragma unroll
        for (int r = 0; r < 4; r++) dst[(size_t)r * 512] = f2h(acc[i][j][r] + bias);
      }
    }
  }
}

// ---- fused attention: out[b][q][d] = (sum_k exp(QK^T) V) / rowsum.
// grid 256 (b=bid&7, q-tile=bid>>3: 64 q-rows), 512 threads (8 waves).
// Wave w: qh=w&1 (32-q half), kg=w>>1 (k-group in QKT / d-quarter in PV).
__global__ __launch_bounds__(512, 2) void attn_fused_kernel(
    const unsigned short* __restrict__ Qg,  // [8][2048][512] fp16
    const unsigned short* __restrict__ Kg,  // [8][2048][512] fp16
    const unsigned short* __restrict__ Vt,  // [8][64][512][32] bf16 tiled
    float* __restrict__ out) {              // [8][2048][512] fp32
  __shared__ alignas(16) unsigned short SB[4][16384];  // 4x32KB stage ring
  __shared__ alignas(16) unsigned short Ps[8192];      // P [64q][128k] bf16 swz
  __shared__ float rsw[4][64];

  const int t = threadIdx.x;
  const int lane = t & 63;
  const int w = t >> 6;
  const int fm = lane & 15;
  const int g = lane >> 4;
  const int qh = w & 1;
  const int kg = w >> 1;
  const int b = blockIdx.x & 7;
  const int q0 = (blockIdx.x >> 3) << 6;

  const unsigned short* Qb = Qg + ((size_t)b * 2048 + q0) * 512;
  const unsigned short* Kb = Kg + (size_t)b * 2048 * 512;
  const unsigned short* Vb = Vt + (size_t)b * 2048 * 512;

  // per-thread staging offsets (4 rounds x 512 thr x 16B = 32KB/unit)
  int ksrc[4], qsrc[4]; unsigned int sdst[4];
#pragma unroll
  for (int r = 0; r < 4; ++r) {
    const int L = r * 8192 + t * 16;  // byte offset within a 32KB unit
    sdst[r] = L >> 1;
    const int kr = L >> 8;            // K unit rows (256 B)
    ksrc[r] = kr * 512 + (((L & 255) ^ ((kr & 7) << 4)) >> 1);
    const int qr = L >> 10;           // Q rows (1024 B)
    qsrc[r] = qr * 512 + (((L & 1023) ^ ((qr & 7) << 4)) >> 1);
  }

  // ---- prologue: stage Q rows 0..31 -> SB0, rows 32..63 -> SB1 ----
#pragma unroll
  for (int r = 0; r < 4; ++r) load_lds16(Qb + qsrc[r], &SB[0][sdst[r]]);
#pragma unroll
  for (int r = 0; r < 4; ++r) load_lds16(Qb + 32 * 512 + qsrc[r], &SB[1][sdst[r]]);
  asm volatile("s_waitcnt vmcnt(0)" ::: "memory");
  __builtin_amdgcn_s_barrier();
  __builtin_amdgcn_sched_barrier(0);

  const int swz = (fm & 7) << 4;  // row&7 == fm&7 for all frag rows used
  f16x8 qf[2][16];  // full Q hoist: [q-frag][d-chunk], 128 VGPRs
#pragma unroll
  for (int j = 0; j < 2; ++j) {
    const char* qbase = (const char*)SB[qh] + (j * 16 + fm) * 1024;
#pragma unroll
    for (int ds = 0; ds < 16; ++ds)
      qf[j][ds] = *(const f16x8*)(qbase + ((ds * 64 + g * 16) ^ swz));
  }
  asm volatile("s_waitcnt lgkmcnt(0)" ::: "memory");
  __builtin_amdgcn_s_barrier();
  __builtin_amdgcn_sched_barrier(0);

  // stage kt0 phases 0,1 (K-unit0 -> SB0, K-unit1 -> SB1)
#pragma unroll
  for (int r = 0; r < 4; ++r) load_lds16(Kb + ksrc[r], &SB[0][sdst[r]]);
#pragma unroll
  for (int r = 0; r < 4; ++r) load_lds16(Kb + 128 + ksrc[r], &SB[1][sdst[r]]);

  f32x4 oacc[2][8];
#pragma unroll
  for (int i = 0; i < 2; ++i)
#pragma unroll
    for (int jj = 0; jj < 8; ++jj) oacc[i][jj] = {0.f, 0.f, 0.f, 0.f};
  float psum0 = 0.f, psum1 = 0.f;
  f32x4 sacc[2][2];

  for (int kt = 0; kt < 16; ++kt) {
    const size_t kbase = (size_t)kt * 65536;  // kt*128*512 elements
#pragma unroll
    for (int u = 0; u < 8; ++u) {
      // ---- issue phase p+2 loads into slot (u+2)&3 (2-phase lead) ----
      unsigned short* nxt = SB[(u + 2) & 3];
      if (u == 0) {
#pragma unroll
        for (int r = 0; r < 4; ++r)
          load_lds16(Kb + kbase + 2 * 128 + ksrc[r], &nxt[sdst[r]]);
      } else if (u == 1) {
#pragma unroll
        for (int r = 0; r < 4; ++r)
          load_lds16(Kb + kbase + 3 * 128 + ksrc[r], &nxt[sdst[r]]);
      } else if (u < 6) {
        const unsigned short* vs = Vb + (size_t)(kt * 4 + (u - 2)) * 16384;
#pragma unroll
        for (int r = 0; r < 4; ++r) load_lds16(vs + sdst[r], &nxt[sdst[r]]);
      } else if (u == 6) {
        if (kt < 15) {
#pragma unroll
          for (int r = 0; r < 4; ++r)
            load_lds16(Kb + kbase + 65536 + ksrc[r], &nxt[sdst[r]]);
        }
      } else {
        if (kt < 15) {
#pragma unroll
          for (int r = 0; r < 4; ++r)
            load_lds16(Kb + kbase + 65536 + 128 + ksrc[r], &nxt[sdst[r]]);
        }
      }
      // ---- counted wait: drain cur's 4 loads; keep 8 (p+1,p+2) in flight ----
      if (u >= 6 && kt == 15) {
        if (u == 6) asm volatile("s_waitcnt vmcnt(4)" ::: "memory");
        else        asm volatile("s_waitcnt vmcnt(0)" ::: "memory");
      } else {
        asm volatile("s_waitcnt vmcnt(8)" ::: "memory");
      }
      __builtin_amdgcn_s_barrier();         // ONE barrier per phase
      __builtin_amdgcn_sched_barrier(0);

      const unsigned short* cur = SB[u & 3];
      if (u < 4) {
        // ---- QKT phase: S^T[k:kg*32+32][q:qh*32+32] += K-unit_u x Q_u ----
        if (u == 0) {
          sacc[0][0] = {0.f, 0.f, 0.f, 0.f}; sacc[0][1] = {0.f, 0.f, 0.f, 0.f};
          sacc[1][0] = {0.f, 0.f, 0.f, 0.f}; sacc[1][1] = {0.f, 0.f, 0.f, 0.f};
        }
        __builtin_amdgcn_s_setprio(1);
#pragma unroll
        for (int s = 0; s < 4; ++s) {
          const int off = (s * 64 + g * 16) ^ swz;
          const f16x8 a0 = *(const f16x8*)((const char*)cur + (kg * 32 + fm) * 256 + off);
          const f16x8 a1 = *(const f16x8*)((const char*)cur + (kg * 32 + 16 + fm) * 256 + off);
          const f16x8 b0 = qf[0][u * 4 + s];
          const f16x8 b1 = qf[1][u * 4 + s];
          sacc[0][0] = __builtin_amdgcn_mfma_f32_16x16x32_f16(a0, b0, sacc[0][0], 0, 0, 0);
          sacc[0][1] = __builtin_amdgcn_mfma_f32_16x16x32_f16(a0, b1, sacc[0][1], 0, 0, 0);
          sacc[1][0] = __builtin_amdgcn_mfma_f32_16x16x32_f16(a1, b0, sacc[1][0], 0, 0, 0);
          sacc[1][1] = __builtin_amdgcn_mfma_f32_16x16x32_f16(a1, b1, sacc[1][1], 0, 0, 0);
        }
        __builtin_amdgcn_s_setprio(0);
        if (u == 3) {
          // exp -> bf16 P (swizzled) + rowsum partials
#pragma unroll
          for (int i = 0; i < 2; ++i)
#pragma unroll
            for (int j = 0; j < 2; ++j) {
              const int q = qh * 32 + j * 16 + fm;
              const int k2 = (kg * 32 + i * 16 + g * 4) * 2;
              union { unsigned short h[4]; short4 s4; } uu;
              float s0 = 0.f;
#pragma unroll
              for (int r = 0; r < 4; ++r) {
                const unsigned short pb = f2bf(__expf(sacc[i][j][r]));
                uu.h[r] = pb; s0 += bf2f(pb);
              }
              if (j == 0) psum0 += s0; else psum1 += s0;
              *(short4*)((char*)Ps + q * 256 + (k2 ^ swz)) = uu.s4;
            }
          asm volatile("s_waitcnt lgkmcnt(0)" ::: "memory");  // Ps visible
        }
      } else {
        // ---- PV phase: out[q 32-half][d 128-qtr] += P(k-slice) x V-unit ----
        const int ju = u - 4;
        const bf16x8 p0 = *(const bf16x8*)((const char*)Ps +
            (qh * 32 + fm) * 256 + ((ju * 64 + g * 16) ^ swz));
        const bf16x8 p1 = *(const bf16x8*)((const char*)Ps +
            (qh * 32 + 16 + fm) * 256 + ((ju * 64 + g * 16) ^ swz));
        __builtin_amdgcn_s_setprio(1);
#pragma unroll
        for (int jj = 0; jj < 8; ++jj) {
          const bf16x8 vf = *(const bf16x8*)((const char*)cur +
              (kg * 128 + jj * 16 + fm) * 64 + g * 16);
          oacc[0][jj] = __builtin_amdgcn_mfma_f32_16x16x32_bf16(p0, vf, oacc[0][jj], 0, 0, 0);
          oacc[1][jj] = __builtin_amdgcn_mfma_f32_16x16x32_bf16(p1, vf, oacc[1][jj], 0, 0, 0);
        }
        __builtin_amdgcn_s_setprio(0);
      }
    }
  }

  // ---- rowsum reduce: quads (shuffle) then k-groups (LDS) ----
  psum0 += __shfl_xor(psum0, 16); psum0 += __shfl_xor(psum0, 32);
  psum1 += __shfl_xor(psum1, 16); psum1 += __shfl_xor(psum1, 32);
  if (g == 0) {
    rsw[kg][qh * 32 + fm] = psum0;
    rsw[kg][qh * 32 + 16 + fm] = psum1;
  }
  __syncthreads();

  // ---- normalize + store: row q = qh*32+i*16+g*4+r, col d = kg*128+jj*16+fm
  float* ob = out + ((size_t)b * 2048 + q0) * 512;
#pragma unroll
  for (int i = 0; i < 2; ++i) {
    float inv[4];
#pragma unroll
    for (int r = 0; r < 4; ++r) {
      const int q = qh * 32 + i * 16 + g * 4 + r;
      inv[r] = 1.0f / (rsw[0][q] + rsw[1][q] + rsw[2][q] + rsw[3][q]);
    }
#pragma unroll
    for (int jj = 0; jj < 8; ++jj) {
      const int d = kg * 128 + jj * 16 + fm;
#pragma unroll
      for (int r = 0; r < 4; ++r)
        ob[(size_t)(qh * 32 + i * 16 + g * 4 + r) * 512 + d] = oacc[i][jj][r] * inv[r];
    }
  }
}

extern "C" void kernel_launch(void* const* d_in, const int* in_sizes, int n_in,
                              void* d_out, int out_size, void* d_ws, size_t ws_size,
                              hipStream_t stream) {
  const float* x  = (const float*)d_in[0];
  const float* Wq = (const float*)d_in[1];
  const float* bq = (const float*)d_in[2];
  const float* Wk = (const float*)d_in[3];
  const float* bk = (const float*)d_in[4];
  const float* Wv = (const float*)d_in[5];
  const float* bv = (const float*)d_in[6];
  float* out = (float*)d_out;

  const size_t SZ = (size_t)16384 * 512 * 2;  // 16.78 MB (half-prec [16384,512])
  char* p = (char*)d_ws;
  unsigned short* xh = (unsigned short*)p; p += SZ;
  unsigned short* Wt = (unsigned short*)p; p += (size_t)3 * 512 * 512 * 2;
  unsigned short* Qb = (unsigned short*)p; p += SZ;              // fp16 [token][512]
  unsigned short* Kb = (unsigned short*)p; p += SZ;              // fp16 [token][512]
  unsigned short* VT = (unsigned short*)p; p += SZ;              // bf16 tiled [b][s/32][d][s%32]

  convx_kernel<<<8192, 256, 0, stream>>>(x, xh);
  convw_kernel<<<dim3(16, 16, 3), dim3(32, 8), 0, stream>>>(Wq, Wk, Wv, Wt);
  gemm_qkv_kernel<<<dim3(128, 12), 256, 0, stream>>>(xh, Wt, Qb, Kb, VT, bq, bk, bv);
  attn_fused_kernel<<<256, 512, 0, stream>>>(Qb, Kb, VT, out);
}